// Round 2
// 71.926 us; speedup vs baseline: 1.0185x; 1.0185x over previous
//
#include <hip/hip_runtime.h>
#include <math.h>

#define BATCH 32
#define PTS   64
#define NPHI  8192
#define NS    4          // phi-streams per thread
#define NP    2          // stream PAIRS per thread (packed fp32, 2 streams/pair)

// Kill mul+add -> fma contraction file-wide. Scalar paths used __f*_rn
// intrinsics (already contraction-proof); the new float2 paths use plain
// vector ops and MUST NOT contract, or bits change vs the validated
// absmax 0.1988525. Explicit __builtin_elementwise_fma is used only where
// the original had __builtin_fmaf.
#pragma clang fp contract(off)

typedef float f32x2 __attribute__((ext_vector_type(2)));

static __device__ __forceinline__ f32x2 splat2(float x) {
    f32x2 r; r.x = x; r.y = x; return r;
}

// ---------- fp64-core sincos (phi only — NS per thread at setup) ----------
// Validated bit-faithful to numpy/JAX fp32 trig in rounds 3-12. q0/q1 feed
// every edge with pole-amplified sensitivity (sin phi near 1: ulp 6e-8),
// so phi's trig must stay at fp64 accuracy. UNCHANGED from the 72.7us kernel.
__device__ __forceinline__ void sincosf_f64(float xf, float* s, float* c) {
    const double PIO2_HI = 1.57079632679489661923e+00;
    const double PIO2_LO = 6.12323399573676603587e-17;

    const float kf = __builtin_rintf(__fmul_rn(xf, 0.63661977236758138243f));
    const int   qi = (int)kf;
    const double kd = (double)kf;
    const double x  = (double)xf;

    double r = __builtin_fma(-kd, PIO2_HI, x);
    r = __builtin_fma(-kd, PIO2_LO, r);
    const double r2 = r * r;

    double ps = -2.50507602534068634195e-08;
    ps = __builtin_fma(ps, r2,  2.75573137070700676789e-06);
    ps = __builtin_fma(ps, r2, -1.98412698298579493134e-04);
    ps = __builtin_fma(ps, r2,  8.33333333332248946124e-03);
    ps = __builtin_fma(ps, r2, -1.66666666666666324348e-01);
    const double sinr = __builtin_fma(r * r2, ps, r);

    double pc =  2.08757232129817482790e-09;
    pc = __builtin_fma(pc, r2, -2.75573143513906633035e-07);
    pc = __builtin_fma(pc, r2,  2.48015872894767294178e-05);
    pc = __builtin_fma(pc, r2, -1.38888888888741095749e-03);
    pc = __builtin_fma(pc, r2,  4.16666666666666019037e-02);
    const double cosr = __builtin_fma(r2 * r2, pc, __builtin_fma(-0.5, r2, 1.0));

    const float sf = (float)sinr, cf = (float)cosr;
    const bool sw = (qi & 1);
    const float ss = sw ? cf : sf;
    const float cc = sw ? sf : cf;
    *s = (qi & 2)       ? -ss : ss;
    *c = ((qi + 1) & 2) ? -cc : cc;
}

// ---------- packed fp32 sincos for edge args: 2 streams per call ----------
// Per-COMPONENT arithmetic is op-for-op identical to the validated R7-R12
// sincos32 (same coeffs, same op order, same rounding): every vector
// mul/add here is one IEEE fp32 op per lane (contract off), every
// elementwise_fma matches an original __builtin_fmaf. The packing only
// changes which INSTRUCTION carries the op (v_pk_* VOP3P), not its bits.
// Quadrant select + sign-xor stay scalar per component (not packable),
// identical to the R12-validated lowering.
__device__ __forceinline__ void sincos32v2(f32x2 x, f32x2* s, f32x2* c) {
    const float C1 = 1.5707969665527344f;    // exact-product reduction const
    const float C2 = -6.3975783777e-7f;      // pi/2 - C1

    const f32x2 t = x * 0.63661977236758f;           // pk_mul
    f32x2 kf;
    kf.x = __builtin_rintf(t.x);                     // v_rndne (scalar-only)
    kf.y = __builtin_rintf(t.y);
    const int qx = (int)kf.x;
    const int qy = (int)kf.y;
    const f32x2 nkf = -kf;                           // exact negation
    const f32x2 r1 = __builtin_elementwise_fma(nkf, splat2(C1), x);   // exact
    const f32x2 r  = __builtin_elementwise_fma(nkf, splat2(C2), r1);
    const f32x2 r2 = r * r;

    f32x2 ps = __builtin_elementwise_fma(splat2(2.75573137e-06f), r2,
                                         splat2(-1.98412698e-04f));
    ps = __builtin_elementwise_fma(ps, r2, splat2( 8.33333333e-03f));
    ps = __builtin_elementwise_fma(ps, r2, splat2(-1.66666667e-01f));
    const f32x2 rr2 = r * r2;
    const f32x2 sr = __builtin_elementwise_fma(rr2, ps, r);

    f32x2 pc = __builtin_elementwise_fma(splat2(-2.75573144e-07f), r2,
                                         splat2( 2.48015873e-05f));
    pc = __builtin_elementwise_fma(pc, r2, splat2(-1.38888889e-03f));
    pc = __builtin_elementwise_fma(pc, r2, splat2( 4.16666667e-02f));
    const f32x2 r4 = r2 * r2;
    const f32x2 h  = 0.5f * r2;
    const f32x2 u  = __builtin_elementwise_fma(r4, pc, -h);
    const f32x2 cr = 1.0f + u;

    // quadrant lowering: scalar per component, identical to R12 (sign-via-xor)
    const bool swx = (qx & 1), swy = (qy & 1);
    const float ssx = swx ? cr.x : sr.x;
    const float ccx = swx ? sr.x : cr.x;
    const float ssy = swy ? cr.y : sr.y;
    const float ccy = swy ? sr.y : cr.y;
    const unsigned ssgx = ((unsigned)qx << 30) & 0x80000000u;
    const unsigned csgx = ((unsigned)(qx + 1) << 30) & 0x80000000u;
    const unsigned ssgy = ((unsigned)qy << 30) & 0x80000000u;
    const unsigned csgy = ((unsigned)(qy + 1) << 30) & 0x80000000u;
    f32x2 so, co;
    so.x = __uint_as_float(__float_as_uint(ssx) ^ ssgx);
    so.y = __uint_as_float(__float_as_uint(ssy) ^ ssgy);
    co.x = __uint_as_float(__float_as_uint(ccx) ^ csgx);
    co.y = __uint_as_float(__float_as_uint(ccy) ^ csgy);
    *s = so;
    *c = co;
}

// One thread per (b, n-quad): phi-streams n0 + j*2048, j=0..3, ALL 64 edges,
// same structure/order as the 72.7us kernel. NEW this round: the 4 streams
// are carried as 2 float2 pairs so the mul/add/fma arithmetic lowers to
// packed-fp32 VOP3P (v_pk_*), halving issue slots for the packable ~70% of
// the instruction stream. Per-stream VALUES are bit-identical (contract off,
// explicit fma only where original had fma; accumulation still edge order
// 0..63 per stream; mask still bit-exact 1e-4 on the exact 3-op ddq).
__global__ __launch_bounds__(256, 1) void scatter_polygon_kernel(
    const float* __restrict__ points,   // [B, P, 2]
    const float* __restrict__ phi,      // [N]
    float* __restrict__ out)            // [B, 2, N]
{
    __shared__ float2 spts[PTS];

    const int b = blockIdx.y;
    const int tid = threadIdx.x;
    const int n0 = blockIdx.x * 256 + tid;      // grid.x = NPHI/NS/256 = 8

    if (tid < PTS) {
        spts[tid] = reinterpret_cast<const float2*>(points)[b * PTS + tid];
    }
    __syncthreads();

    // pair k holds streams j=2k (.x) and j=2k+1 (.y)
    f32x2 q0[NP], q1[NP], sc[NP], s0[NP], c0[NP], aR[NP], aI[NP];

    #pragma unroll
    for (int k = 0; k < NP; ++k) {
        float s_, c_;
        sincosf_f64(phi[n0 + (2 * k)     * (NPHI / NS)], &s_, &c_);
        q0[k].x = c_;
        q1[k].x = __fsub_rn(s_, 1.0f);
        sincosf_f64(phi[n0 + (2 * k + 1) * (NPHI / NS)], &s_, &c_);
        q0[k].y = c_;
        q1[k].y = __fsub_rn(s_, 1.0f);
        sc[k].x = 1.0f / fabsf(__fadd_rn(__fmul_rn(q0[k].x, q0[k].x),
                                         __fmul_rn(q1[k].x, q1[k].x)));
        sc[k].y = 1.0f / fabsf(__fadd_rn(__fmul_rn(q0[k].y, q0[k].y),
                                         __fmul_rn(q1[k].y, q1[k].y)));
        aR[k] = splat2(0.0f);
        aI[k] = splat2(0.0f);
    }

    // previous vertex = points[b, P-1] (roll by 1)
    const float2 pv = spts[PTS - 1];
    float xp = pv.x, yp = pv.y;
    #pragma unroll
    for (int k = 0; k < NP; ++k) {
        const f32x2 t0 = xp * q0[k];            // mul (exact)
        const f32x2 t1 = yp * q1[k];            // mul (exact)
        const f32x2 dp = t0 + t1;               // add (exact, no contract)
        sincos32v2(dp, &s0[k], &c0[k]);
    }

    // hand-pipelined LDS read by one iteration (covers ds_read latency
    // at 1 wave/SIMD)
    float2 v = spts[0];

    #pragma unroll 4
    for (int p = 0; p < PTS; ++p) {
        const float2 vn = spts[(p + 1) & (PTS - 1)];   // prefetch next
        const float dx = __fsub_rn(v.x, xp);           // n-independent: shared
        const float dy = __fsub_rn(v.y, yp);

        #pragma unroll
        for (int k = 0; k < NP; ++k) {   // 2 packed pairs = 4 streams
            const f32x2 m0 = v.x * q0[k];              // pk_mul
            const f32x2 m1 = v.y * q1[k];              // pk_mul
            const f32x2 dp = m0 + m1;                  // pk_add (exact 3-op dp)
            f32x2 s1, c1;
            sincos32v2(dp, &s1, &c1);
            const f32x2 e0 = dx * q0[k];
            const f32x2 e1 = dy * q1[k];
            const f32x2 ddq = e0 + e1;                 // exact 3-op ddq (mask!)
            const f32x2 f0 = dy * q0[k];
            const f32x2 f1 = dx * q1[k];
            const f32x2 ddqc = f0 - f1;                // exact 3-op ddqc
            f32x2 inv;
            inv.x = __builtin_amdgcn_rcpf(ddq.x);      // trans, scalar-only
            inv.y = __builtin_amdgcn_rcpf(ddq.y);
            const bool mx = (fabsf(ddq.x) >= 1e-4f);   // bit-exact 1e-4 mask
            const bool my = (fabsf(ddq.y) >= 1e-4f);
            const f32x2 dR = c0[k] - c1;               // pk_sub
            const f32x2 dI = s0[k] - s1;
            const f32x2 dRi = dR * inv;                // mul BEFORE select,
            const f32x2 dIi = dI * inv;                //   as in original
            f32x2 gR, gI;
            gR.x = mx ? dRi.x : s0[k].x;
            gR.y = my ? dRi.y : s0[k].y;
            gI.x = mx ? dIi.x : -c0[k].x;
            gI.y = my ? dIi.y : -c0[k].y;
            aR[k] = __builtin_elementwise_fma(ddqc, gR, aR[k]);  // pk_fma
            aI[k] = __builtin_elementwise_fma(ddqc, gI, aI[k]);
            s0[k] = s1;
            c0[k] = c1;
        }

        xp = v.x; yp = v.y;
        v = vn;
    }

    float* o = out + (size_t)b * 2 * NPHI;
    #pragma unroll
    for (int k = 0; k < NP; ++k) {
        o[n0 + (2 * k)     * (NPHI / NS)]        = sc[k].x * aR[k].x;  // real
        o[n0 + (2 * k + 1) * (NPHI / NS)]        = sc[k].y * aR[k].y;
        o[NPHI + n0 + (2 * k)     * (NPHI / NS)] = sc[k].x * aI[k].x;  // imag
        o[NPHI + n0 + (2 * k + 1) * (NPHI / NS)] = sc[k].y * aI[k].y;
    }
}

extern "C" void kernel_launch(void* const* d_in, const int* in_sizes, int n_in,
                              void* d_out, int out_size, void* d_ws, size_t ws_size,
                              hipStream_t stream) {
    const float* points = (const float*)d_in[0];  // [32, 64, 2] fp32
    const float* phi    = (const float*)d_in[1];  // [8192] fp32
    float* out          = (float*)d_out;          // [32, 2, 8192] fp32

    dim3 grid(NPHI / NS / 256, BATCH);   // 8 x 32 = 256 blocks, 1 block/CU
    scatter_polygon_kernel<<<grid, 256, 0, stream>>>(points, phi, out);
}

// Round 3
// 70.995 us; speedup vs baseline: 1.0319x; 1.0131x over previous
//
#include <hip/hip_runtime.h>
#include <math.h>

#define BATCH 32
#define PTS   64
#define NPHI  8192
#define NS    2          // phi-streams per thread (R2: was 4; halved for 2 waves/SIMD)
#define NP    1          // stream PAIRS per thread (packed fp32, 2 streams/pair)

// Kill mul+add -> fma contraction file-wide. Scalar paths used __f*_rn
// intrinsics (already contraction-proof); the float2 paths use plain
// vector ops and MUST NOT contract, or bits change vs the validated
// absmax 0.1988525. Explicit __builtin_elementwise_fma is used only where
// the original had __builtin_fmaf.
#pragma clang fp contract(off)

typedef float f32x2 __attribute__((ext_vector_type(2)));

static __device__ __forceinline__ f32x2 splat2(float x) {
    f32x2 r; r.x = x; r.y = x; return r;
}

// ---------- fp64-core sincos (phi only — NS per thread at setup) ----------
// Validated bit-faithful to numpy/JAX fp32 trig in rounds 3-12. q0/q1 feed
// every edge with pole-amplified sensitivity (sin phi near 1: ulp 6e-8),
// so phi's trig must stay at fp64 accuracy. UNCHANGED from the 72.7us kernel.
__device__ __forceinline__ void sincosf_f64(float xf, float* s, float* c) {
    const double PIO2_HI = 1.57079632679489661923e+00;
    const double PIO2_LO = 6.12323399573676603587e-17;

    const float kf = __builtin_rintf(__fmul_rn(xf, 0.63661977236758138243f));
    const int   qi = (int)kf;
    const double kd = (double)kf;
    const double x  = (double)xf;

    double r = __builtin_fma(-kd, PIO2_HI, x);
    r = __builtin_fma(-kd, PIO2_LO, r);
    const double r2 = r * r;

    double ps = -2.50507602534068634195e-08;
    ps = __builtin_fma(ps, r2,  2.75573137070700676789e-06);
    ps = __builtin_fma(ps, r2, -1.98412698298579493134e-04);
    ps = __builtin_fma(ps, r2,  8.33333333332248946124e-03);
    ps = __builtin_fma(ps, r2, -1.66666666666666324348e-01);
    const double sinr = __builtin_fma(r * r2, ps, r);

    double pc =  2.08757232129817482790e-09;
    pc = __builtin_fma(pc, r2, -2.75573143513906633035e-07);
    pc = __builtin_fma(pc, r2,  2.48015872894767294178e-05);
    pc = __builtin_fma(pc, r2, -1.38888888888741095749e-03);
    pc = __builtin_fma(pc, r2,  4.16666666666666019037e-02);
    const double cosr = __builtin_fma(r2 * r2, pc, __builtin_fma(-0.5, r2, 1.0));

    const float sf = (float)sinr, cf = (float)cosr;
    const bool sw = (qi & 1);
    const float ss = sw ? cf : sf;
    const float cc = sw ? sf : cf;
    *s = (qi & 2)       ? -ss : ss;
    *c = ((qi + 1) & 2) ? -cc : cc;
}

// ---------- packed fp32 sincos for edge args: 2 streams per call ----------
// Per-COMPONENT arithmetic is op-for-op identical to the validated R7-R12
// sincos32 (same coeffs, same op order, same rounding): every vector
// mul/add here is one IEEE fp32 op per lane (contract off), every
// elementwise_fma matches an original __builtin_fmaf. The packing only
// changes which INSTRUCTION carries the op (v_pk_* VOP3P), not its bits.
// Quadrant select + sign-xor stay scalar per component (not packable),
// identical to the R12-validated lowering.
__device__ __forceinline__ void sincos32v2(f32x2 x, f32x2* s, f32x2* c) {
    const float C1 = 1.5707969665527344f;    // exact-product reduction const
    const float C2 = -6.3975783777e-7f;      // pi/2 - C1

    const f32x2 t = x * 0.63661977236758f;           // pk_mul
    f32x2 kf;
    kf.x = __builtin_rintf(t.x);                     // v_rndne (scalar-only)
    kf.y = __builtin_rintf(t.y);
    const int qx = (int)kf.x;
    const int qy = (int)kf.y;
    const f32x2 nkf = -kf;                           // exact negation
    const f32x2 r1 = __builtin_elementwise_fma(nkf, splat2(C1), x);   // exact
    const f32x2 r  = __builtin_elementwise_fma(nkf, splat2(C2), r1);
    const f32x2 r2 = r * r;

    f32x2 ps = __builtin_elementwise_fma(splat2(2.75573137e-06f), r2,
                                         splat2(-1.98412698e-04f));
    ps = __builtin_elementwise_fma(ps, r2, splat2( 8.33333333e-03f));
    ps = __builtin_elementwise_fma(ps, r2, splat2(-1.66666667e-01f));
    const f32x2 rr2 = r * r2;
    const f32x2 sr = __builtin_elementwise_fma(rr2, ps, r);

    f32x2 pc = __builtin_elementwise_fma(splat2(-2.75573144e-07f), r2,
                                         splat2( 2.48015873e-05f));
    pc = __builtin_elementwise_fma(pc, r2, splat2(-1.38888889e-03f));
    pc = __builtin_elementwise_fma(pc, r2, splat2( 4.16666667e-02f));
    const f32x2 r4 = r2 * r2;
    const f32x2 h  = 0.5f * r2;
    const f32x2 u  = __builtin_elementwise_fma(r4, pc, -h);
    const f32x2 cr = 1.0f + u;

    // quadrant lowering: scalar per component, identical to R12 (sign-via-xor)
    const bool swx = (qx & 1), swy = (qy & 1);
    const float ssx = swx ? cr.x : sr.x;
    const float ccx = swx ? sr.x : cr.x;
    const float ssy = swy ? cr.y : sr.y;
    const float ccy = swy ? sr.y : cr.y;
    const unsigned ssgx = ((unsigned)qx << 30) & 0x80000000u;
    const unsigned csgx = ((unsigned)(qx + 1) << 30) & 0x80000000u;
    const unsigned ssgy = ((unsigned)qy << 30) & 0x80000000u;
    const unsigned csgy = ((unsigned)(qy + 1) << 30) & 0x80000000u;
    f32x2 so, co;
    so.x = __uint_as_float(__float_as_uint(ssx) ^ ssgx);
    so.y = __uint_as_float(__float_as_uint(ssy) ^ ssgy);
    co.x = __uint_as_float(__float_as_uint(ccx) ^ csgx);
    co.y = __uint_as_float(__float_as_uint(ccy) ^ csgy);
    *s = so;
    *c = co;
}

// R2 structural change: NS 4 -> 2 streams/thread, thread count 65536 ->
// 131072, occupancy 1 -> 2 waves/SIMD (512 blocks = 2 blocks/CU). Packed
// R0/R1 measurement showed instruction-count cuts are near-neutral -> the
// kernel is fp32-ALU-cycle bound at VALUBusy~78%; the remaining 22% is
// stall (sincos dep chains, trans-pipe rcp, ds_read) that a second wave
// per SIMD can fill. Per-stream arithmetic and edge order are UNCHANGED
// (bit-identical, validated absmax 0.1988525); only the stream->thread
// mapping changed. Shared per-edge work (ds_read/dx/dy/loop) duplication:
// ~+4% of per-eval instructions (vs +15-20% for R12's NS=1 that regressed).
__global__ __launch_bounds__(256, 2) void scatter_polygon_kernel(
    const float* __restrict__ points,   // [B, P, 2]
    const float* __restrict__ phi,      // [N]
    float* __restrict__ out)            // [B, 2, N]
{
    __shared__ float2 spts[PTS];

    const int b = blockIdx.y;
    const int tid = threadIdx.x;
    const int n0 = blockIdx.x * 256 + tid;      // grid.x = NPHI/NS/256 = 16

    if (tid < PTS) {
        spts[tid] = reinterpret_cast<const float2*>(points)[b * PTS + tid];
    }
    __syncthreads();

    // pair k holds streams j=2k (.x) and j=2k+1 (.y); stream j -> phi index
    // n0 + j*(NPHI/NS) with NPHI/NS = 4096
    f32x2 q0[NP], q1[NP], sc[NP], s0[NP], c0[NP], aR[NP], aI[NP];

    #pragma unroll
    for (int k = 0; k < NP; ++k) {
        float s_, c_;
        sincosf_f64(phi[n0 + (2 * k)     * (NPHI / NS)], &s_, &c_);
        q0[k].x = c_;
        q1[k].x = __fsub_rn(s_, 1.0f);
        sincosf_f64(phi[n0 + (2 * k + 1) * (NPHI / NS)], &s_, &c_);
        q0[k].y = c_;
        q1[k].y = __fsub_rn(s_, 1.0f);
        sc[k].x = 1.0f / fabsf(__fadd_rn(__fmul_rn(q0[k].x, q0[k].x),
                                         __fmul_rn(q1[k].x, q1[k].x)));
        sc[k].y = 1.0f / fabsf(__fadd_rn(__fmul_rn(q0[k].y, q0[k].y),
                                         __fmul_rn(q1[k].y, q1[k].y)));
        aR[k] = splat2(0.0f);
        aI[k] = splat2(0.0f);
    }

    // previous vertex = points[b, P-1] (roll by 1)
    const float2 pv = spts[PTS - 1];
    float xp = pv.x, yp = pv.y;
    #pragma unroll
    for (int k = 0; k < NP; ++k) {
        const f32x2 t0 = xp * q0[k];            // mul (exact)
        const f32x2 t1 = yp * q1[k];            // mul (exact)
        const f32x2 dp = t0 + t1;               // add (exact, no contract)
        sincos32v2(dp, &s0[k], &c0[k]);
    }

    // hand-pipelined LDS read by one iteration (covers ds_read latency)
    float2 v = spts[0];

    #pragma unroll 4
    for (int p = 0; p < PTS; ++p) {
        const float2 vn = spts[(p + 1) & (PTS - 1)];   // prefetch next
        const float dx = __fsub_rn(v.x, xp);           // n-independent: shared
        const float dy = __fsub_rn(v.y, yp);

        #pragma unroll
        for (int k = 0; k < NP; ++k) {   // 1 packed pair = 2 streams
            const f32x2 m0 = v.x * q0[k];              // pk_mul
            const f32x2 m1 = v.y * q1[k];              // pk_mul
            const f32x2 dp = m0 + m1;                  // pk_add (exact 3-op dp)
            f32x2 s1, c1;
            sincos32v2(dp, &s1, &c1);
            const f32x2 e0 = dx * q0[k];
            const f32x2 e1 = dy * q1[k];
            const f32x2 ddq = e0 + e1;                 // exact 3-op ddq (mask!)
            const f32x2 f0 = dy * q0[k];
            const f32x2 f1 = dx * q1[k];
            const f32x2 ddqc = f0 - f1;                // exact 3-op ddqc
            f32x2 inv;
            inv.x = __builtin_amdgcn_rcpf(ddq.x);      // trans, scalar-only
            inv.y = __builtin_amdgcn_rcpf(ddq.y);
            const bool mx = (fabsf(ddq.x) >= 1e-4f);   // bit-exact 1e-4 mask
            const bool my = (fabsf(ddq.y) >= 1e-4f);
            const f32x2 dR = c0[k] - c1;               // pk_sub
            const f32x2 dI = s0[k] - s1;
            const f32x2 dRi = dR * inv;                // mul BEFORE select,
            const f32x2 dIi = dI * inv;                //   as in original
            f32x2 gR, gI;
            gR.x = mx ? dRi.x : s0[k].x;
            gR.y = my ? dRi.y : s0[k].y;
            gI.x = mx ? dIi.x : -c0[k].x;
            gI.y = my ? dIi.y : -c0[k].y;
            aR[k] = __builtin_elementwise_fma(ddqc, gR, aR[k]);  // pk_fma
            aI[k] = __builtin_elementwise_fma(ddqc, gI, aI[k]);
            s0[k] = s1;
            c0[k] = c1;
        }

        xp = v.x; yp = v.y;
        v = vn;
    }

    float* o = out + (size_t)b * 2 * NPHI;
    #pragma unroll
    for (int k = 0; k < NP; ++k) {
        o[n0 + (2 * k)     * (NPHI / NS)]        = sc[k].x * aR[k].x;  // real
        o[n0 + (2 * k + 1) * (NPHI / NS)]        = sc[k].y * aR[k].y;
        o[NPHI + n0 + (2 * k)     * (NPHI / NS)] = sc[k].x * aI[k].x;  // imag
        o[NPHI + n0 + (2 * k + 1) * (NPHI / NS)] = sc[k].y * aI[k].y;
    }
}

extern "C" void kernel_launch(void* const* d_in, const int* in_sizes, int n_in,
                              void* d_out, int out_size, void* d_ws, size_t ws_size,
                              hipStream_t stream) {
    const float* points = (const float*)d_in[0];  // [32, 64, 2] fp32
    const float* phi    = (const float*)d_in[1];  // [8192] fp32
    float* out          = (float*)d_out;          // [32, 2, 8192] fp32

    dim3 grid(NPHI / NS / 256, BATCH);   // 16 x 32 = 512 blocks, 2 blocks/CU
    scatter_polygon_kernel<<<grid, 256, 0, stream>>>(points, phi, out);
}